// Round 7
// baseline (264.452 us; speedup 1.0000x reference)
//
#include <hip/hip_runtime.h>

#define NPG   2048
#define XP    72              // xlds/w pitch (bf16): 144B rows, 16B-aligned
#define TP    136             // xt/kt pitch: 272B rows, 16B-aligned

typedef short bf16x8 __attribute__((ext_vector_type(8)));
typedef float f32x4  __attribute__((ext_vector_type(4)));
typedef unsigned short u16x8 __attribute__((ext_vector_type(8)));
typedef unsigned short u16x4 __attribute__((ext_vector_type(4)));

__device__ __forceinline__ unsigned short f2b(float f) {
    unsigned int u = __float_as_uint(f);
    return (unsigned short)((u + 0x7FFFu + ((u >> 16) & 1u)) >> 16);  // RN-even
}
__device__ __forceinline__ float b2f(unsigned short u) {
    return __uint_as_float((unsigned)u << 16);
}

// ---------------------------------------------------------------------------
// kv_kernel: 512 thr, grid 1024 = (b,h,chunk4); 512 nodes per block (4 tiles).
// Produces: q~ [N][256] bf16 (qbuf), kvT[c][d] 64x64 f32 partial, ksum[64] f32
// partial, vsum[64] f32 partial (h==0 blocks only).
// ---------------------------------------------------------------------------
extern "C" __global__ __launch_bounds__(512, 4)
void kv_kernel(const float* __restrict__ x,
               const float* __restrict__ Wk_w, const float* __restrict__ Wk_b,
               const float* __restrict__ Wq_w, const float* __restrict__ Wq_b,
               unsigned short* __restrict__ qbuf,
               float* __restrict__ kvp, float* __restrict__ ksump,
               float* __restrict__ vsump)
{
    __shared__ __align__(16) unsigned short wk[64 * XP];
    __shared__ __align__(16) unsigned short wq[64 * XP];
    __shared__ __align__(16) unsigned short xlds[128 * XP];
    __shared__ __align__(16) unsigned short xt[64 * TP];   // x~^T [c][n]
    __shared__ __align__(16) unsigned short kt[64 * TP];   // k~^T [d][n]
    __shared__ __align__(16) float blds[128];              // bias: k [0:64), q [64:128)
    __shared__ float kred[8][64];
    __shared__ float vred[8][64];

    const int t  = threadIdx.x;
    const int l  = t & 63;
    const int w  = t >> 6;
    const int lr = l & 15;
    const int lg = l >> 4;
    const int g    = blockIdx.x;
    const int xcd  = g & 7;
    const int rest = g >> 3;        // 0..127
    const int bhi  = rest & 7;
    const int h     = (rest >> 3) & 3;
    const int chunk = rest >> 5;    // 0..3 (512 nodes each)
    const int b     = bhi * 8 + xcd;
    const int bh    = b * 4 + h;

    // stage Wk/Wq head rows + biases
    for (int idx = t; idx < 64 * 64; idx += 512) {
        int r = idx >> 6, c = idx & 63;
        wk[r * XP + c] = f2b(Wk_w[(size_t)(h * 64 + r) * 64 + c]);
        wq[r * XP + c] = f2b(Wq_w[(size_t)(h * 64 + r) * 64 + c]);
    }
    if (t < 64) {
        blds[t]      = Wk_b[h * 64 + t];
        blds[64 + t] = Wq_b[h * 64 + t];
    }

    // kv tile ownership: wave w -> C-tiles (ct, dt0), (ct, dt1)
    const int ct  = w >> 1;
    const int dt0 = (w & 1) * 2;
    const int dt1 = dt0 + 1;
    f32x4 kvacc[2] = {};
    float ksacc[4][4] = {};
    float vsacc[4] = {};

    const int cpc = t & 63;          // transpose column c
    const int n0  = (t >> 6) * 16;   // transpose node sub-range
    const int src0 = lr + ((lg & 1) * 32);   // butterfly source lanes
    const int src1 = src0 + 16;
    const bool hi  = (lg >> 1) & 1;

    const size_t node_base = (size_t)b * NPG + (size_t)chunk * 512;
    const float4* xg0 = (const float4*)(x + node_base * 64);

    // prologue: stage tile 0
    float4 rx[4];
#pragma unroll
    for (int j = 0; j < 4; ++j) rx[j] = xg0[j * 512 + t];
#pragma unroll
    for (int j = 0; j < 4; ++j) {
        int n = j * 32 + (t >> 4), c = (t & 15) * 4;
        u16x4 pv = { f2b(rx[j].x), f2b(rx[j].y), f2b(rx[j].z), f2b(rx[j].w) };
        *(u16x4*)&xlds[n * XP + c] = pv;
        vsacc[0] += rx[j].x; vsacc[1] += rx[j].y;
        vsacc[2] += rx[j].z; vsacc[3] += rx[j].w;
    }
    __syncthreads();

    for (int tt = 0; tt < 4; ++tt) {
        // T: transpose-fill xt[c][n] from xlds
        {
            u16x8 w0, w1;
#pragma unroll
            for (int k2 = 0; k2 < 8; ++k2) w0[k2] = xlds[(n0 + k2) * XP + cpc];
#pragma unroll
            for (int k2 = 0; k2 < 8; ++k2) w1[k2] = xlds[(n0 + 8 + k2) * XP + cpc];
            *(u16x8*)&xt[cpc * TP + n0]     = w0;
            *(u16x8*)&xt[cpc * TP + n0 + 8] = w1;
        }

        const int ncol = w * 16 + lr;
        bf16x8 xb[2];
#pragma unroll
        for (int ks = 0; ks < 2; ++ks)
            xb[ks] = *(const bf16x8*)&xlds[ncol * XP + ks * 32 + lg * 8];

        // ---- k-proj + norm + ksum accum + kt write ----
        {
            f32x4 pacc[4] = {};
#pragma unroll
            for (int ks = 0; ks < 2; ++ks)
#pragma unroll
                for (int mt = 0; mt < 4; ++mt) {
                    bf16x8 wfr = *(const bf16x8*)&wk[(mt * 16 + lr) * XP + ks * 32 + lg * 8];
                    pacc[mt] = __builtin_amdgcn_mfma_f32_16x16x32_bf16(wfr, xb[ks], pacc[mt], 0, 0, 0);
                }
            float ss = 0.f;
#pragma unroll
            for (int mt = 0; mt < 4; ++mt) {
                f32x4 bk = *(const f32x4*)&blds[mt * 16 + 4 * lg];
#pragma unroll
                for (int i = 0; i < 4; ++i) {
                    float v = pacc[mt][i] + bk[i];
                    pacc[mt][i] = v;
                    ss = fmaf(v, v, ss);
                }
            }
            ss += __shfl_xor(ss, 16, 64);
            ss += __shfl_xor(ss, 32, 64);
            const float sc = rsqrtf(ss);
#pragma unroll
            for (int mt = 0; mt < 4; ++mt)
#pragma unroll
                for (int i = 0; i < 4; ++i) {
                    float kn = pacc[mt][i] * sc;
                    ksacc[mt][i] += kn;
                    kt[(mt * 16 + 4 * lg + i) * TP + ncol] = f2b(kn);
                }
        }

        // ---- q-proj + norm + butterfly + q~ store ----
        {
            f32x4 pacc[4] = {};
#pragma unroll
            for (int ks = 0; ks < 2; ++ks)
#pragma unroll
                for (int mt = 0; mt < 4; ++mt) {
                    bf16x8 wfr = *(const bf16x8*)&wq[(mt * 16 + lr) * XP + ks * 32 + lg * 8];
                    pacc[mt] = __builtin_amdgcn_mfma_f32_16x16x32_bf16(wfr, xb[ks], pacc[mt], 0, 0, 0);
                }
            float ss = 0.f;
#pragma unroll
            for (int mt = 0; mt < 4; ++mt) {
                f32x4 bq = *(const f32x4*)&blds[64 + mt * 16 + 4 * lg];
#pragma unroll
                for (int i = 0; i < 4; ++i) {
                    float v = pacc[mt][i] + bq[i];
                    pacc[mt][i] = v;
                    ss = fmaf(v, v, ss);
                }
            }
            ss += __shfl_xor(ss, 16, 64);
            ss += __shfl_xor(ss, 32, 64);
            const float sc = rsqrtf(ss);

            unsigned pw[4][2];
#pragma unroll
            for (int mt = 0; mt < 4; ++mt) {
                pw[mt][0] = (unsigned)f2b(pacc[mt][0] * sc) | ((unsigned)f2b(pacc[mt][1] * sc) << 16);
                pw[mt][1] = (unsigned)f2b(pacc[mt][2] * sc) | ((unsigned)f2b(pacc[mt][3] * sc) << 16);
            }
            unsigned r0[4][2], r1[4][2];
#pragma unroll
            for (int mt = 0; mt < 4; ++mt)
#pragma unroll
                for (int p = 0; p < 2; ++p) {
                    r0[mt][p] = __shfl(pw[mt][p], src0, 64);
                    r1[mt][p] = __shfl(pw[mt][p], src1, 64);
                }
            union { unsigned u[4]; u16x8 v; } a0, a1;
            a0.u[0] = hi ? r0[1][0] : r0[0][0];
            a0.u[1] = hi ? r0[1][1] : r0[0][1];
            a0.u[2] = hi ? r1[1][0] : r1[0][0];
            a0.u[3] = hi ? r1[1][1] : r1[0][1];
            a1.u[0] = hi ? r0[3][0] : r0[2][0];
            a1.u[1] = hi ? r0[3][1] : r0[2][1];
            a1.u[2] = hi ? r1[3][0] : r1[2][0];
            a1.u[3] = hi ? r1[3][1] : r1[2][1];

            const size_t node = node_base + (size_t)tt * 128 + ncol;
            unsigned short* qp = qbuf + node * 256 + h * 64 + lg * 8;
            *(u16x8*)qp        = a0.v;
            *(u16x8*)(qp + 32) = a1.v;
        }
        __syncthreads();

        const bool more = (tt + 1) < 4;
        if (more) {
            const float4* xg = xg0 + (size_t)(tt + 1) * 128 * 16;
#pragma unroll
            for (int j = 0; j < 4; ++j) rx[j] = xg[j * 512 + t];
        }

        // G: kv GEMM (reads xt/kt only)
#pragma unroll
        for (int ks = 0; ks < 4; ++ks) {
            const int ko = ks * 32 + lg * 8;
            bf16x8 a  = *(const bf16x8*)&xt[(ct  * 16 + lr) * TP + ko];
            bf16x8 b0 = *(const bf16x8*)&kt[(dt0 * 16 + lr) * TP + ko];
            bf16x8 b1 = *(const bf16x8*)&kt[(dt1 * 16 + lr) * TP + ko];
            kvacc[0] = __builtin_amdgcn_mfma_f32_16x16x32_bf16(a, b0, kvacc[0], 0, 0, 0);
            kvacc[1] = __builtin_amdgcn_mfma_f32_16x16x32_bf16(a, b1, kvacc[1], 0, 0, 0);
        }

        if (more) {
#pragma unroll
            for (int j = 0; j < 4; ++j) {
                int n = j * 32 + (t >> 4), c = (t & 15) * 4;
                u16x4 pv = { f2b(rx[j].x), f2b(rx[j].y), f2b(rx[j].z), f2b(rx[j].w) };
                *(u16x4*)&xlds[n * XP + c] = pv;
                vsacc[0] += rx[j].x; vsacc[1] += rx[j].y;
                vsacc[2] += rx[j].z; vsacc[3] += rx[j].w;
            }
        }
        __syncthreads();
    }

    // ---- reductions ----
#pragma unroll
    for (int mt = 0; mt < 4; ++mt)
#pragma unroll
        for (int i = 0; i < 4; ++i) {
            float v = ksacc[mt][i];
            v += __shfl_xor(v, 1, 64);
            v += __shfl_xor(v, 2, 64);
            v += __shfl_xor(v, 4, 64);
            v += __shfl_xor(v, 8, 64);
            if (lr == 0) kred[w][mt * 16 + 4 * lg + i] = v;
        }
#pragma unroll
    for (int j = 0; j < 4; ++j) {
        float v = vsacc[j];
        v += __shfl_xor(v, 16, 64);
        v += __shfl_xor(v, 32, 64);
        if (lg == 0) vred[w][lr * 4 + j] = v;
    }
    __syncthreads();

    // ---- stores ----
    float* kvbase = kvp + ((size_t)chunk * 256 + bh) * 4096;
#pragma unroll
    for (int i = 0; i < 4; ++i) {
        kvbase[(size_t)(ct * 16 + 4 * lg + i) * 64 + dt0 * 16 + lr] = kvacc[0][i];
        kvbase[(size_t)(ct * 16 + 4 * lg + i) * 64 + dt1 * 16 + lr] = kvacc[1][i];
    }
    if (t < 64) {
        float s = 0.f;
#pragma unroll
        for (int ww = 0; ww < 8; ++ww) s += kred[ww][t];
        ksump[((size_t)chunk * 256 + bh) * 64 + t] = s;
        if (h == 0) {
            float s2 = 0.f;
#pragma unroll
            for (int ww = 0; ww < 8; ++ww) s2 += vred[ww][t];
            vsump[((size_t)chunk * 64 + b) * 64 + t] = s2;
        }
    }
}

// ---------------------------------------------------------------------------
// out_kernel: pure streaming, no LDS, no barriers. 256 thr = 4 waves; wave w
// owns 128 nodes. Per 16-node group: load q~ frags, den = q~.ksum (in-frag dot
// + 2 shfl), 8 MFMA vs kv frags, (+vsum)/den, store.
// ---------------------------------------------------------------------------
extern "C" __global__ __launch_bounds__(256, 4)
void out_kernel(const unsigned short* __restrict__ qbuf,
                const int* __restrict__ n_nodes,
                const float* __restrict__ kvp, const float* __restrict__ ksump,
                const float* __restrict__ vsump,
                float* __restrict__ out)
{
    const int t  = threadIdx.x;
    const int l  = t & 63;
    const int w  = t >> 6;          // 0..3
    const int lr = l & 15;
    const int lg = l >> 4;
    const int g    = blockIdx.x;
    const int xcd  = g & 7;
    const int r    = g >> 3;        // 0..127
    const int bhi  = r & 7;
    const int hq   = r >> 3;        // 0..15
    const int h    = hq & 3;
    const int quarter = hq >> 2;    // 0..3
    const int b    = bhi * 8 + xcd;
    const int bh   = b * 4 + h;
    const int chunk = quarter * 4 + w;   // 0..15, 128 nodes each

    // kv B-frags: sum of 4 chunk partials (f32), then bf16
    bf16x8 kvf[4][2];
#pragma unroll
    for (int ctc = 0; ctc < 4; ++ctc)
#pragma unroll
        for (int ks = 0; ks < 2; ++ks) {
            f32x4 s0 = {}, s1 = {};
#pragma unroll
            for (int p = 0; p < 4; ++p) {
                const float* kp = kvp + ((size_t)p * 256 + bh) * 4096
                                + (size_t)(ctc * 16 + lr) * 64 + ks * 32 + lg * 8;
                s0 += *(const f32x4*)kp;
                s1 += *(const f32x4*)(kp + 4);
            }
            bf16x8 f;
#pragma unroll
            for (int j = 0; j < 4; ++j) f[j]     = (short)f2b(s0[j]);
#pragma unroll
            for (int j = 0; j < 4; ++j) f[4 + j] = (short)f2b(s1[j]);
            kvf[ctc][ks] = f;
        }
    // ksum at this lane's d-slice: d = ks*32 + lg*8 + j
    float ksr[16];
#pragma unroll
    for (int ks = 0; ks < 2; ++ks)
#pragma unroll
        for (int j = 0; j < 8; ++j) {
            const int d = ks * 32 + lg * 8 + j;
            float s = 0.f;
#pragma unroll
            for (int p = 0; p < 4; ++p)
                s += ksump[((size_t)p * 256 + bh) * 64 + d];
            ksr[ks * 8 + j] = s;
        }
    // vsum at c = ct*16+lr
    float vsr[4];
#pragma unroll
    for (int ctc = 0; ctc < 4; ++ctc) {
        float s = 0.f;
#pragma unroll
        for (int p = 0; p < 4; ++p)
            s += vsump[((size_t)p * 64 + b) * 64 + ctc * 16 + lr];
        vsr[ctc] = s;
    }
    const float npg = (float)n_nodes[b];

    const size_t node_base = (size_t)b * NPG + (size_t)chunk * 128;

    for (int gg = 0; gg < 8; ++gg) {
        const size_t node = node_base + gg * 16 + lr;
        const unsigned short* qp = qbuf + node * 256 + h * 64 + lg * 8;
        bf16x8 qa0 = *(const bf16x8*)qp;
        bf16x8 qa1 = *(const bf16x8*)(qp + 32);

        // denominator: q~ . ksum + n
        float den = 0.f;
#pragma unroll
        for (int j = 0; j < 8; ++j) {
            den = fmaf(b2f((unsigned short)qa0[j]), ksr[j],     den);
            den = fmaf(b2f((unsigned short)qa1[j]), ksr[8 + j], den);
        }
        den += __shfl_xor(den, 16, 64);
        den += __shfl_xor(den, 32, 64);
        den += npg;   // den for node (base + gg*16 + lr), in all lanes

        f32x4 nacc[4] = {};
#pragma unroll
        for (int ctc = 0; ctc < 4; ++ctc) {
            nacc[ctc] = __builtin_amdgcn_mfma_f32_16x16x32_bf16(qa0, kvf[ctc][0], nacc[ctc], 0, 0, 0);
            nacc[ctc] = __builtin_amdgcn_mfma_f32_16x16x32_bf16(qa1, kvf[ctc][1], nacc[ctc], 0, 0, 0);
        }

        float* op = out + (node_base + gg * 16) * 256 + h * 64;
#pragma unroll
        for (int i = 0; i < 4; ++i) {
            const float den_i = __shfl(den, 4 * lg + i, 64);
            const float rd = 1.0f / den_i;
#pragma unroll
            for (int ctc = 0; ctc < 4; ++ctc)
                op[(size_t)(4 * lg + i) * 256 + ctc * 16 + lr] = (nacc[ctc][i] + vsr[ctc]) * rd;
        }
    }
}

extern "C" void kernel_launch(void* const* d_in, const int* in_sizes, int n_in,
                              void* d_out, int out_size, void* d_ws, size_t ws_size,
                              hipStream_t stream) {
    const float* x     = (const float*)d_in[0];
    const float* Wq_w  = (const float*)d_in[1];
    const float* Wq_b  = (const float*)d_in[2];
    const float* Wk_w  = (const float*)d_in[3];
    const float* Wk_b  = (const float*)d_in[4];
    const int* n_nodes = (const int*)d_in[5];
    float* out = (float*)d_out;

    // workspace layout
    unsigned short* qbuf = (unsigned short*)d_ws;                    // 131072*256 bf16 = 67.1 MB
    float* kvp  = (float*)((char*)d_ws + (size_t)67108864);          // [4][256][4096] f32 = 16.8 MB
    float* ksum = kvp + (size_t)4 * 256 * 4096;                      // [4][256][64]
    float* vsum = ksum + (size_t)4 * 256 * 64;                       // [4][64][64]

    hipLaunchKernelGGL(kv_kernel, dim3(1024), dim3(512), 0, stream,
                       x, Wk_w, Wk_b, Wq_w, Wq_b, qbuf, kvp, ksum, vsum);
    hipLaunchKernelGGL(out_kernel, dim3(1024), dim3(256), 0, stream,
                       qbuf, n_nodes, kvp, ksum, vsum, out);
}